// Round 9
// baseline (605.754 us; speedup 1.0000x reference)
//
#include <hip/hip_runtime.h>
#include <stdint.h>

// Problem: ComplexDepthwiseBatchNorm  N=16384, C=8, F=257
// Layout: x[N][C*F] row-major; NCOLS = 2056 columns per row.
// Dtype of x / W / out is detected ON DEVICE (bf16 vs fp32) — see detect_kernel.
#define NROWS   16384
#define NCOLS   2056
#define NG      257          // groups of 8 elements per row (2056/8)
#define EPSV    1e-6f
#define DELTA_MAX 1e8f
#define SR      64           // row slices for stats (NROWS/SR = 256 rows/slice)

typedef float    f32x4v __attribute__((ext_vector_type(4)));
typedef float    f32x8v __attribute__((ext_vector_type(8)));
typedef uint32_t u32x4v __attribute__((ext_vector_type(4)));

__device__ __forceinline__ float bf_lo(uint32_t u) {
    return __builtin_bit_cast(float, u << 16);
}
__device__ __forceinline__ float bf_hi(uint32_t u) {
    return __builtin_bit_cast(float, u & 0xffff0000u);
}
__device__ __forceinline__ float bf1(uint16_t u) {
    return __builtin_bit_cast(float, (uint32_t)u << 16);
}
// round-to-nearest-even bf16 pair pack: lo -> bits[15:0], hi -> bits[31:16]
__device__ __forceinline__ uint32_t bf16pair(float lo, float hi) {
    uint32_t ul = __builtin_bit_cast(uint32_t, lo);
    uint32_t uh = __builtin_bit_cast(uint32_t, hi);
    ul = (ul + 0x7fffu + ((ul >> 16) & 1u)) >> 16;
    uh = (uh + 0x7fffu + ((uh >> 16) & 1u)) & 0xffff0000u;
    return ul | uh;
}

// ---------------- Pass 0: dtype detection ----------------
// flags[0]=1 iff x is fp32; flags[1]=1 iff W/B are fp32.
__global__ __launch_bounds__(512) void detect_kernel(
    const uint32_t* __restrict__ xr_u, const uint32_t* __restrict__ wrr_u,
    int* __restrict__ flags)
{
    __shared__ int cnt[2];
    if (threadIdx.x < 2) cnt[threadIdx.x] = 0;
    __syncthreads();
    const int part = threadIdx.x >> 8;                    // 0: x, 1: Wrr
    const uint32_t u = part ? wrr_u[threadIdx.x & 255] : xr_u[threadIdx.x & 255];
    const uint32_t e = (u >> 7) & 0xFFu;
    const int ok = (e >= 100u && e <= 131u) ? 1 : 0;
    atomicAdd(&cnt[part], ok);
    __syncthreads();
    if (threadIdx.x == 0) {
        flags[0] = (cnt[0] < 128) ? 1 : 0;
        flags[1] = (cnt[1] < 128) ? 1 : 0;
    }
}

// ---------------- Pass 1: per-column sums (tile-stationary, deep MLP) -------
// Structure identical to the proven round-1/7 config (grid dim3(SR,33),
// block 256; shfl_xor over lane bits 3..5 -> LDS combine -> 320 atomics),
// register f32x8 accumulators, __launch_bounds__(256,4).
// ONE change this round: ISSUE-ALL-THEN-CONSUME. The k-loop's 16 loads are
// issued back-to-back into register arrays (compile-time indices only) before
// any accumulation. MLP model that fits all 9 rounds: unroll-2 had ~4 loads
// x 16 B = 64 B in flight/wave; 8448 waves x 64 B / 375 ns HBM latency =
// 1.4 TB/s — the measured wall. Concurrency was scaled 8x in earlier rounds
// but depth never was. 16 loads in flight -> 256 B/wave -> HBM-limited.
// Loads are PLAIN (x must allocate into L3 so apply's read stays warm).
__global__ __launch_bounds__(256, 4) void stats_kernel(
    const void* __restrict__ xr_p, const void* __restrict__ xi_p,
    const int* __restrict__ flags, float* __restrict__ sums)
{
    const int rs = blockIdx.x;          // 0..SR-1
    const int ct = blockIdx.y;          // 0..32
    const int t  = threadIdx.x;
    const int rbase = rs * (NROWS / SR);   // 256 rows per slice

    f32x8v sr  = {0.f,0.f,0.f,0.f,0.f,0.f,0.f,0.f};
    f32x8v si  = sr, srr = sr, sri = sr, sii = sr;

    const bool isfp32 = (flags[0] != 0);

    if (ct < 32) {
        const int grp = ct * 8 + (t & 7);
        const int rl  = t >> 3;             // 0..31
        if (!isfp32) {
            const u32x4v* __restrict__ xr4 = (const u32x4v*)xr_p;
            const u32x4v* __restrict__ xi4 = (const u32x4v*)xi_p;
            const size_t gb = (size_t)(rbase + rl) * NG + grp;
            u32x4v A[8], B[8];
            #pragma unroll
            for (int k = 0; k < 8; ++k) {       // 16 loads issued up front
                A[k] = xr4[gb + (size_t)(32 * k) * NG];
                B[k] = xi4[gb + (size_t)(32 * k) * NG];
            }
            #pragma unroll
            for (int k = 0; k < 8; ++k) {
                #pragma unroll
                for (int j = 0; j < 4; ++j) {
                    const float r0 = bf_lo(A[k][j]), r1 = bf_hi(A[k][j]);
                    const float i0 = bf_lo(B[k][j]), i1 = bf_hi(B[k][j]);
                    sr [2*j]   += r0;       si [2*j]   += i0;
                    srr[2*j]   += r0*r0;    sri[2*j]   += r0*i0;    sii[2*j]   += i0*i0;
                    sr [2*j+1] += r1;       si [2*j+1] += i1;
                    srr[2*j+1] += r1*r1;    sri[2*j+1] += r1*i1;    sii[2*j+1] += i1*i1;
                }
            }
        } else {
            const f32x4v* __restrict__ xr4 = (const f32x4v*)xr_p;
            const f32x4v* __restrict__ xi4 = (const f32x4v*)xi_p;
            #pragma unroll
            for (int h = 0; h < 2; ++h) {       // 2 chunks x 4 iters: 16 loads each
                f32x4v A0[4], A1[4], B0[4], B1[4];
                #pragma unroll
                for (int k = 0; k < 4; ++k) {
                    const size_t g = (size_t)(rbase + rl + 32*(4*h + k)) * 514 + 2*grp;
                    A0[k] = xr4[g];  A1[k] = xr4[g + 1];
                    B0[k] = xi4[g];  B1[k] = xi4[g + 1];
                }
                #pragma unroll
                for (int k = 0; k < 4; ++k) {
                    #pragma unroll
                    for (int j = 0; j < 4; ++j) {
                        sr [j]   += A0[k][j];            si [j]   += B0[k][j];
                        srr[j]   += A0[k][j]*A0[k][j];   sri[j]   += A0[k][j]*B0[k][j];
                        sii[j]   += B0[k][j]*B0[k][j];
                        sr [4+j] += A1[k][j];            si [4+j] += B1[k][j];
                        srr[4+j] += A1[k][j]*A1[k][j];   sri[4+j] += A1[k][j]*B1[k][j];
                        sii[4+j] += B1[k][j]*B1[k][j];
                    }
                }
            }
        }
        // reduce over the 8 row-lanes sharing this group (lane bits 3..5)
        #pragma unroll
        for (int m = 8; m <= 32; m <<= 1) {
            #pragma unroll
            for (int e = 0; e < 8; ++e) {
                sr [e] += __shfl_xor(sr [e], m, 64);
                si [e] += __shfl_xor(si [e], m, 64);
                srr[e] += __shfl_xor(srr[e], m, 64);
                sri[e] += __shfl_xor(sri[e], m, 64);
                sii[e] += __shfl_xor(sii[e], m, 64);
            }
        }
    } else {
        // leftover group 256 (columns 2048..2055): one row per thread
        if (!isfp32) {
            const u32x4v* __restrict__ xr4 = (const u32x4v*)xr_p;
            const u32x4v* __restrict__ xi4 = (const u32x4v*)xi_p;
            const size_t g = (size_t)(rbase + t) * NG + 256;
            const u32x4v a = xr4[g];
            const u32x4v b = xi4[g];
            #pragma unroll
            for (int j = 0; j < 4; ++j) {
                const float r0 = bf_lo(a[j]), r1 = bf_hi(a[j]);
                const float i0 = bf_lo(b[j]), i1 = bf_hi(b[j]);
                sr [2*j]   += r0;       si [2*j]   += i0;
                srr[2*j]   += r0*r0;    sri[2*j]   += r0*i0;    sii[2*j]   += i0*i0;
                sr [2*j+1] += r1;       si [2*j+1] += i1;
                srr[2*j+1] += r1*r1;    sri[2*j+1] += r1*i1;    sii[2*j+1] += i1*i1;
            }
        } else {
            const f32x4v* __restrict__ xr4 = (const f32x4v*)xr_p;
            const f32x4v* __restrict__ xi4 = (const f32x4v*)xi_p;
            const size_t g = (size_t)(rbase + t) * 514 + 512;
            const f32x4v a0 = xr4[g], a1 = xr4[g + 1];
            const f32x4v b0 = xi4[g], b1 = xi4[g + 1];
            #pragma unroll
            for (int j = 0; j < 4; ++j) {
                sr [j]   += a0[j];        si [j]   += b0[j];
                srr[j]   += a0[j]*a0[j];  sri[j]   += a0[j]*b0[j];  sii[j]   += b0[j]*b0[j];
                sr [4+j] += a1[j];        si [4+j] += b1[j];
                srr[4+j] += a1[j]*a1[j];  sri[4+j] += a1[j]*b1[j];
                sii[4+j] += b1[j]*b1[j];
            }
        }
        // full 64-lane reduction
        #pragma unroll
        for (int m = 1; m <= 32; m <<= 1) {
            #pragma unroll
            for (int e = 0; e < 8; ++e) {
                sr [e] += __shfl_xor(sr [e], m, 64);
                si [e] += __shfl_xor(si [e], m, 64);
                srr[e] += __shfl_xor(srr[e], m, 64);
                sri[e] += __shfl_xor(sri[e], m, 64);
                sii[e] += __shfl_xor(sii[e], m, 64);
            }
        }
    }

    // cross-wave combine: per-wave representatives -> LDS -> sum 4 -> atomic
    __shared__ float red[4][320];
    const int wv = t >> 6, ln = t & 63;
    if (ct < 32) {
        if (ln < 8) {
            #pragma unroll
            for (int e = 0; e < 8; ++e) {
                red[wv][ln*40 + 0*8 + e] = sr [e];
                red[wv][ln*40 + 1*8 + e] = si [e];
                red[wv][ln*40 + 2*8 + e] = srr[e];
                red[wv][ln*40 + 3*8 + e] = sri[e];
                red[wv][ln*40 + 4*8 + e] = sii[e];
            }
        }
    } else {
        if (ln == 0) {
            #pragma unroll
            for (int e = 0; e < 8; ++e) {
                red[wv][0*8 + e] = sr [e];
                red[wv][1*8 + e] = si [e];
                red[wv][2*8 + e] = srr[e];
                red[wv][3*8 + e] = sri[e];
                red[wv][4*8 + e] = sii[e];
            }
        }
    }
    __syncthreads();
    const int nvals = (ct < 32) ? 320 : 40;
    for (int idx = t; idx < nvals; idx += 256) {
        const float v = red[0][idx] + red[1][idx] + red[2][idx] + red[3][idx];
        const int gi  = idx / 40;
        const int j   = idx - gi * 40;          // stat*8 + colj
        const int col = (ct * 8 + gi) * 8 + (j & 7);
        atomicAdd(&sums[(j >> 3) * NCOLS + col], v);
    }
}

// ---------------- Pass 2: sums -> per-column coefficients ----------------
__global__ __launch_bounds__(256) void coef_kernel(
    const float* __restrict__ sums,
    const void* __restrict__ Wrr_p, const void* __restrict__ Wri_p,
    const void* __restrict__ Wii_p, const void* __restrict__ Br_p,
    const void* __restrict__ Bi_p,
    const int* __restrict__ flags, float* __restrict__ coef)
{
    const int j = blockIdx.x * 256 + threadIdx.x;
    if (j >= NCOLS) return;
    const float invN = 1.0f / (float)NROWS;
    const float Mr  = sums[0*NCOLS+j] * invN;
    const float Mi  = sums[1*NCOLS+j] * invN;
    const float Vrr = sums[2*NCOLS+j] * invN - Mr * Mr;
    const float Vri = sums[3*NCOLS+j] * invN - Mr * Mi;
    const float Vii = sums[4*NCOLS+j] * invN - Mi * Mi;
    const float tau   = Vrr + Vii;
    const float delta = fminf(fmaxf(Vrr * Vii - Vri * Vri, EPSV), DELTA_MAX);
    const float s   = sqrtf(delta);
    const float t   = sqrtf(tau + 2.0f * s);
    const float rst = 1.0f / (s * t);
    const float Urr = (s + Vii) * rst;
    const float Uii = (s + Vrr) * rst;
    const float Uri = -Vri * rst;

    float wrr, wri, wii, br, bi;
    if (flags[1]) {
        wrr = ((const float*)Wrr_p)[j];  wri = ((const float*)Wri_p)[j];
        wii = ((const float*)Wii_p)[j];
        br  = ((const float*)Br_p)[j];   bi  = ((const float*)Bi_p)[j];
    } else {
        wrr = bf1(((const uint16_t*)Wrr_p)[j]);  wri = bf1(((const uint16_t*)Wri_p)[j]);
        wii = bf1(((const uint16_t*)Wii_p)[j]);
        br  = bf1(((const uint16_t*)Br_p)[j]);   bi  = bf1(((const uint16_t*)Bi_p)[j]);
    }
    const float Zrr = wrr * Urr + wri * Uri;
    const float Zri = wrr * Uri + wri * Uii;
    const float Zir = wri * Urr + wii * Uri;
    const float Zii = wri * Uri + wii * Uii;
    coef[0*NCOLS+j] = Zrr;
    coef[1*NCOLS+j] = Zri;
    coef[2*NCOLS+j] = Zir;
    coef[3*NCOLS+j] = Zii;
    coef[4*NCOLS+j] = br - Zrr * Mr - Zri * Mi;
    coef[5*NCOLS+j] = bi - Zir * Mr - Zii * Mi;
}

// ---------------- Pass 3: apply (column-stationary, deep MLP, NT stores) ----
// grid 2056 x block 256, T = 526336 = 2048*257 bijection, flat-contiguous.
// Same issue-all-then-consume restructure (chunks of 4 iters -> 8 loads in
// flight vs ~4). Loads plain (x is L3-warm from stats); stores NT (y never
// re-read; measured ~17 us faster than plain in rounds 1/3).
__global__ __launch_bounds__(256) void apply_kernel(
    const void* __restrict__ xr_p, const void* __restrict__ xi_p,
    const float* __restrict__ coef, const int* __restrict__ flags,
    void* __restrict__ out_p)
{
    const int tid = blockIdx.x * 256 + threadIdx.x;
    const int c  = tid % NG;
    const int r0 = tid / NG;            // [0,2048)
    const int col = c * 8;

    float Z[6][8];
    #pragma unroll
    for (int t = 0; t < 6; ++t) {
        const float4 lo = *(const float4*)(coef + t*NCOLS + col);
        const float4 hi = *(const float4*)(coef + t*NCOLS + col + 4);
        Z[t][0]=lo.x; Z[t][1]=lo.y; Z[t][2]=lo.z; Z[t][3]=lo.w;
        Z[t][4]=hi.x; Z[t][5]=hi.y; Z[t][6]=hi.z; Z[t][7]=hi.w;
    }

    if (flags[0]) {
        // -------- fp32 path --------
        const f32x4v* __restrict__ xr4 = (const f32x4v*)xr_p;
        const f32x4v* __restrict__ xi4 = (const f32x4v*)xi_p;
        f32x4v* yr4 = (f32x4v*)out_p;
        f32x4v* yi4 = yr4 + (size_t)NROWS * 514;   // yi after N*C*F floats
        #pragma unroll
        for (int h = 0; h < 2; ++h) {
            f32x4v A0[4], A1[4], B0[4], B1[4];
            #pragma unroll
            for (int k = 0; k < 4; ++k) {
                const size_t g = (size_t)(r0 + ((4*h + k) << 11)) * 514 + 2 * c;
                A0[k] = xr4[g];  A1[k] = xr4[g + 1];
                B0[k] = xi4[g];  B1[k] = xi4[g + 1];
            }
            #pragma unroll
            for (int k = 0; k < 4; ++k) {
                const size_t g = (size_t)(r0 + ((4*h + k) << 11)) * 514 + 2 * c;
                float yrv[8], yiv[8];
                #pragma unroll
                for (int j = 0; j < 4; ++j) {
                    yrv[j]   = Z[0][j]  *A0[k][j] + Z[1][j]  *B0[k][j] + Z[4][j];
                    yiv[j]   = Z[2][j]  *A0[k][j] + Z[3][j]  *B0[k][j] + Z[5][j];
                    yrv[4+j] = Z[0][4+j]*A1[k][j] + Z[1][4+j]*B1[k][j] + Z[4][4+j];
                    yiv[4+j] = Z[2][4+j]*A1[k][j] + Z[3][4+j]*B1[k][j] + Z[5][4+j];
                }
                const f32x4v s0 = {yrv[0], yrv[1], yrv[2], yrv[3]};
                const f32x4v s1 = {yrv[4], yrv[5], yrv[6], yrv[7]};
                const f32x4v t0 = {yiv[0], yiv[1], yiv[2], yiv[3]};
                const f32x4v t1 = {yiv[4], yiv[5], yiv[6], yiv[7]};
                __builtin_nontemporal_store(s0, yr4 + g);
                __builtin_nontemporal_store(s1, yr4 + g + 1);
                __builtin_nontemporal_store(t0, yi4 + g);
                __builtin_nontemporal_store(t1, yi4 + g + 1);
            }
        }
    } else {
        // -------- bf16 path --------
        const u32x4v* __restrict__ xr4 = (const u32x4v*)xr_p;
        const u32x4v* __restrict__ xi4 = (const u32x4v*)xi_p;
        u32x4v* yr4 = (u32x4v*)out_p;
        u32x4v* yi4 = yr4 + (size_t)NROWS * NG;     // yi after N*C*F bf16
        #pragma unroll
        for (int h = 0; h < 2; ++h) {
            u32x4v A[4], B[4];
            #pragma unroll
            for (int k = 0; k < 4; ++k) {
                const size_t g = (size_t)(r0 + ((4*h + k) << 11)) * NG + c;
                A[k] = xr4[g];
                B[k] = xi4[g];
            }
            #pragma unroll
            for (int k = 0; k < 4; ++k) {
                const size_t g = (size_t)(r0 + ((4*h + k) << 11)) * NG + c;
                uint32_t ou[4], pu[4];
                #pragma unroll
                for (int j = 0; j < 4; ++j) {
                    const int e0 = 2*j, e1 = 2*j + 1;
                    const float xr0 = bf_lo(A[k][j]), xr1 = bf_hi(A[k][j]);
                    const float xi0 = bf_lo(B[k][j]), xi1 = bf_hi(B[k][j]);
                    const float yr0 = Z[0][e0]*xr0 + Z[1][e0]*xi0 + Z[4][e0];
                    const float yi0 = Z[2][e0]*xr0 + Z[3][e0]*xi0 + Z[5][e0];
                    const float yr1 = Z[0][e1]*xr1 + Z[1][e1]*xi1 + Z[4][e1];
                    const float yi1 = Z[2][e1]*xr1 + Z[3][e1]*xi1 + Z[5][e1];
                    ou[j] = bf16pair(yr0, yr1);
                    pu[j] = bf16pair(yi0, yi1);
                }
                const u32x4v o = {ou[0], ou[1], ou[2], ou[3]};
                const u32x4v p = {pu[0], pu[1], pu[2], pu[3]};
                __builtin_nontemporal_store(o, yr4 + g);
                __builtin_nontemporal_store(p, yi4 + g);
            }
        }
    }
}

extern "C" void kernel_launch(void* const* d_in, const int* in_sizes, int n_in,
                              void* d_out, int out_size, void* d_ws, size_t ws_size,
                              hipStream_t stream)
{
    const void* xr_p = d_in[0];
    const void* xi_p = d_in[1];
    const void* Wrr  = d_in[2];
    const void* Wri  = d_in[3];
    const void* Wii  = d_in[4];
    const void* Br   = d_in[5];
    const void* Bi   = d_in[6];

    float* sums  = (float*)d_ws;             // 5 * 2056 f32
    float* coef  = sums + 5 * NCOLS;         // 6 * 2056 f32
    int*   flags = (int*)(coef + 6 * NCOLS); // 2 ints

    detect_kernel<<<1, 512, 0, stream>>>((const uint32_t*)xr_p, (const uint32_t*)Wrr, flags);
    (void)hipMemsetAsync(sums, 0, 5 * NCOLS * sizeof(float), stream);
    stats_kernel<<<dim3(SR, 33), 256, 0, stream>>>(xr_p, xi_p, flags, sums);
    coef_kernel<<<(NCOLS + 255) / 256, 256, 0, stream>>>(sums, Wrr, Wri, Wii, Br, Bi, flags, coef);
    apply_kernel<<<2056, 256, 0, stream>>>(xr_p, xi_p, coef, flags, d_out);
}